// Round 4
// baseline (253.944 us; speedup 1.0000x reference)
//
#include <hip/hip_runtime.h>
#include <math.h>

#define N_RES 768
#define DISTO_BINS 64
#define LDDT_BINS 50
#define DISTO_GRID 2048
#define EXP_GRID 64

// ---------------- Kernel A: distogram CE partial sums ----------------
// One wave processes 4 pairs per chunk (chunk = 256 floats = 4 pairs x 64
// bins); lane l holds float4 [4l,4l+4); lanes 16q..16q+15 hold pair q.
// 4 chunks in flight per iteration for memory-level parallelism.
__global__ __launch_bounds__(256)
void disto_partial_kernel(const float4* __restrict__ logits4,
                          const float* __restrict__ pb,
                          const float* __restrict__ pbm,
                          float* __restrict__ partial) {
    __shared__ float spb[N_RES * 3];
    __shared__ float spm[N_RES];
    for (int k = threadIdx.x; k < N_RES * 3; k += blockDim.x) spb[k] = pb[k];
    for (int k = threadIdx.x; k < N_RES; k += blockDim.x) spm[k] = pbm[k];
    __syncthreads();

    const int lane = threadIdx.x & 63;
    const int wid  = threadIdx.x >> 6;
    const int q    = lane >> 4;    // pair-group 0..3 within wave
    const int gl   = lane & 15;    // lane within group
    const int gw   = blockIdx.x * 4 + wid;
    const int nw   = DISTO_GRID * 4;                 // 8192 waves
    const int nchunks = (N_RES * N_RES) / 4;         // 147456 (= 18 per wave)

    float acc = 0.f;

#define DISTO_PROC(xv4, cc)                                                   \
    {                                                                         \
        float e = __expf(xv4.x) + __expf(xv4.y) + __expf(xv4.z) +             \
                  __expf(xv4.w);                                              \
        e += __shfl_xor(e, 1, 64);                                            \
        e += __shfl_xor(e, 2, 64);                                            \
        e += __shfl_xor(e, 4, 64);                                            \
        e += __shfl_xor(e, 8, 64);                                            \
        int p = (cc) * 4 + q;                                                 \
        int i = p / N_RES;                                                    \
        int j = p - i * N_RES;                                                \
        float dx = spb[3 * i + 0] - spb[3 * j + 0];                           \
        float dy = spb[3 * i + 1] - spb[3 * j + 1];                           \
        float dz = spb[3 * i + 2] - spb[3 * j + 2];                           \
        float d  = sqrtf(dx * dx + dy * dy + dz * dz);                        \
        float t  = ceilf((d - 2.3125f) * 3.2f);                               \
        int bin  = (int)fminf(fmaxf(t, 0.f), 63.f);                           \
        float xs = (bin & 2) ? ((bin & 1) ? xv4.w : xv4.z)                    \
                             : ((bin & 1) ? xv4.y : xv4.x);                   \
        float xv = __shfl(xs, (q << 4) + (bin >> 2), 64);                     \
        if (gl == 0) acc += (__logf(e) - xv) * spm[i] * spm[j];               \
    }

    for (int c0 = gw; c0 < nchunks; c0 += 4 * nw) {
        const int c1 = c0 + nw;
        const int c2 = c0 + 2 * nw;
        const int c3 = c0 + 3 * nw;
        // issue up to 4 loads before any compute (4 outstanding vmem)
        float4 x0 = logits4[(size_t)c0 * 64 + lane];
        float4 x1 = (c1 < nchunks) ? logits4[(size_t)c1 * 64 + lane]
                                   : make_float4(0.f, 0.f, 0.f, 0.f);
        float4 x2 = (c2 < nchunks) ? logits4[(size_t)c2 * 64 + lane]
                                   : make_float4(0.f, 0.f, 0.f, 0.f);
        float4 x3 = (c3 < nchunks) ? logits4[(size_t)c3 * 64 + lane]
                                   : make_float4(0.f, 0.f, 0.f, 0.f);

        DISTO_PROC(x0, c0);
        if (c1 < nchunks) DISTO_PROC(x1, c1);
        if (c2 < nchunks) DISTO_PROC(x2, c2);
        if (c3 < nchunks) DISTO_PROC(x3, c3);
    }
#undef DISTO_PROC

    acc += __shfl_xor(acc, 16, 64);
    acc += __shfl_xor(acc, 32, 64);
    __shared__ float wsum[4];
    if (lane == 0) wsum[wid] = acc;
    __syncthreads();
    if (threadIdx.x == 0)
        partial[blockIdx.x] = wsum[0] + wsum[1] + wsum[2] + wsum[3];
}

// -------- Kernel B: fused per-residue lddt+CE  AND  exp-resolved partials --
// blocks [0, N_RES)            : lddt + CE for residue blockIdx.x -> errm
// blocks [N_RES, N_RES+EXP_GRID): grid-stride exp-resolved partial sums
__global__ __launch_bounds__(128)
void small_losses_kernel(const float* __restrict__ pred37,      // (N,37,3)
                         const float* __restrict__ true37,      // (N,37,3)
                         const float* __restrict__ mask37,      // (N,37)
                         const float* __restrict__ lddt_logits, // (N,50)
                         const float* __restrict__ exl,         // (N,37)
                         const float* __restrict__ a37ex,       // (N,37)
                         float* __restrict__ errm,              // (N)
                         float* __restrict__ expnum,            // (EXP_GRID)
                         float* __restrict__ expden) {          // (EXP_GRID)
    const int tid  = threadIdx.x;
    const int nthr = blockDim.x;
    __shared__ float r1[128], r2[128];

    if (blockIdx.x >= N_RES) {
        // ---- exp-resolved partial sums ----
        const int b = blockIdx.x - N_RES;
        const int gid = b * nthr + tid;
        const int stride = EXP_GRID * nthr;
        const int n = N_RES * 37;
        float num = 0.f, den = 0.f;
        for (int k = gid; k < n; k += stride) {
            float x  = exl[k];
            float m  = mask37[k];
            float ex = a37ex[k];
            float ax = fabsf(x);
            float sp = __logf(1.f + __expf(-ax));   // softplus(-|x|)
            float ls  = sp + fmaxf(-x, 0.f);        // -log_sigmoid(x)
            float lsn = sp + fmaxf(x, 0.f);         // -log_sigmoid(-x)
            float err = m * ls + (1.f - m) * lsn;
            num += err * ex;
            den += ex;
        }
        r1[tid] = num;
        r2[tid] = den;
        __syncthreads();
        for (int s = nthr >> 1; s > 0; s >>= 1) {
            if (tid < s) { r1[tid] += r1[tid + s]; r2[tid] += r2[tid + s]; }
            __syncthreads();
        }
        if (tid == 0) { expnum[b] = r1[0]; expden[b] = r2[0]; }
        return;
    }

    // ---- per-residue lddt + CE ----
    const int i = blockIdx.x;
    const float tix = true37[(i * 37 + 1) * 3 + 0];
    const float tiy = true37[(i * 37 + 1) * 3 + 1];
    const float tiz = true37[(i * 37 + 1) * 3 + 2];
    const float pix = pred37[(i * 37 + 1) * 3 + 0];
    const float piy = pred37[(i * 37 + 1) * 3 + 1];
    const float piz = pred37[(i * 37 + 1) * 3 + 2];
    const float mi  = mask37[i * 37 + 1];

    float scope_sum = 0.f, score_sum = 0.f;
    for (int j = tid; j < N_RES; j += nthr) {
        float mj  = mask37[j * 37 + 1];
        float dtx = tix - true37[(j * 37 + 1) * 3 + 0];
        float dty = tiy - true37[(j * 37 + 1) * 3 + 1];
        float dtz = tiz - true37[(j * 37 + 1) * 3 + 2];
        float dt  = sqrtf(1e-10f + dtx * dtx + dty * dty + dtz * dtz);
        float dpx = pix - pred37[(j * 37 + 1) * 3 + 0];
        float dpy = piy - pred37[(j * 37 + 1) * 3 + 1];
        float dpz = piz - pred37[(j * 37 + 1) * 3 + 2];
        float dp  = sqrtf(1e-10f + dpx * dpx + dpy * dpy + dpz * dpz);
        float scope = (dt < 15.f && j != i) ? (mi * mj) : 0.f;
        float l1 = fabsf(dt - dp);
        float sc = 0.25f * ((l1 < 0.5f ? 1.f : 0.f) + (l1 < 1.f ? 1.f : 0.f) +
                            (l1 < 2.f ? 1.f : 0.f) + (l1 < 4.f ? 1.f : 0.f));
        scope_sum += scope;
        score_sum += scope * sc;
    }

    r1[tid] = scope_sum;
    r2[tid] = score_sum;
    __syncthreads();
    for (int s = nthr >> 1; s > 0; s >>= 1) {
        if (tid < s) { r1[tid] += r1[tid + s]; r2[tid] += r2[tid + s]; }
        __syncthreads();
    }

    __shared__ int binS;
    if (tid == 0) {
        float lddt = (1e-10f + r2[0]) / (1e-10f + r1[0]);
        int bin = (int)floorf(lddt * (float)LDDT_BINS);
        binS = min(max(bin, 0), LDDT_BINS - 1);
    }
    __syncthreads();

    float e = (tid < LDDT_BINS) ? __expf(lddt_logits[i * LDDT_BINS + tid]) : 0.f;
    r1[tid] = e;
    __syncthreads();
    for (int s = nthr >> 1; s > 0; s >>= 1) {
        if (tid < s) r1[tid] += r1[tid + s];
        __syncthreads();
    }
    if (tid == 0) {
        float err = __logf(r1[0]) - lddt_logits[i * LDDT_BINS + binS];
        errm[i] = err * mi;
    }
}

// ---------------- Kernel C: final combine (small reductions only) --------
__global__ __launch_bounds__(256)
void finalize_kernel(const float* __restrict__ partial,  // (DISTO_GRID)
                     const float* __restrict__ pbm,      // (N,)
                     const float* __restrict__ errm,     // (N,)
                     const float* __restrict__ mask37,   // (N,37)
                     const float* __restrict__ expnum,   // (EXP_GRID)
                     const float* __restrict__ expden,   // (EXP_GRID)
                     const float* __restrict__ resolution,
                     float* __restrict__ out) {
    const int tid = threadIdx.x;
    const int nthr = blockDim.x;

    double sd = 0.0, sm = 0.0, se = 0.0, smca = 0.0, num = 0.0, den = 0.0;
    for (int k = tid; k < DISTO_GRID; k += nthr) sd += (double)partial[k];
    for (int k = tid; k < N_RES; k += nthr) {
        sm   += (double)pbm[k];
        se   += (double)errm[k];
        smca += (double)mask37[k * 37 + 1];
    }
    if (tid < EXP_GRID) { num = (double)expnum[tid]; den = (double)expden[tid]; }

    __shared__ double red[256];
    double vals[6] = {sd, sm, se, smca, num, den};
    double tot[6];
    for (int v = 0; v < 6; ++v) {
        red[tid] = vals[v];
        __syncthreads();
        for (int s = nthr >> 1; s > 0; s >>= 1) {
            if (tid < s) red[tid] += red[tid + s];
            __syncthreads();
        }
        tot[v] = red[0];
        __syncthreads();
    }

    if (tid == 0) {
        float res = resolution[0];
        double gate = (res >= 0.1f && res <= 3.0f) ? 1.0 : 0.0;
        double l_disto = tot[0] / (1e-6 + tot[1] * tot[1]);
        double l_plddt = tot[2] / (1e-10 + tot[3]) * gate;
        double l_exp   = tot[4] / (1e-8 + tot[5]) * gate;
        out[0] = (float)(0.3 * l_disto + 0.01 * l_plddt + 0.01 * l_exp);
    }
}

extern "C" void kernel_launch(void* const* d_in, const int* in_sizes, int n_in,
                              void* d_out, int out_size, void* d_ws, size_t ws_size,
                              hipStream_t stream) {
    const float* disto       = (const float*)d_in[0];  // (1,768,768,64)
    const float* pb          = (const float*)d_in[1];  // (1,768,3)
    const float* pbm         = (const float*)d_in[2];  // (1,768)
    const float* lddt_logits = (const float*)d_in[3];  // (1,768,50)
    const float* pred        = (const float*)d_in[4];  // (1,768,37,3)
    const float* truep       = (const float*)d_in[5];  // (1,768,37,3)
    const float* am          = (const float*)d_in[6];  // (1,768,37)
    const float* exl         = (const float*)d_in[7];  // (1,768,37)
    const float* a37         = (const float*)d_in[8];  // (1,768,37)
    const float* resolution  = (const float*)d_in[9];  // (1,)
    float* out = (float*)d_out;

    float* ws      = (float*)d_ws;
    float* partial = ws;                         // DISTO_GRID
    float* errm    = ws + DISTO_GRID;            // N_RES
    float* expnum  = errm + N_RES;               // EXP_GRID
    float* expden  = expnum + EXP_GRID;          // EXP_GRID

    disto_partial_kernel<<<DISTO_GRID, 256, 0, stream>>>(
        (const float4*)disto, pb, pbm, partial);
    small_losses_kernel<<<N_RES + EXP_GRID, 128, 0, stream>>>(
        pred, truep, am, lddt_logits, exl, a37, errm, expnum, expden);
    finalize_kernel<<<1, 256, 0, stream>>>(partial, pbm, errm, am,
                                           expnum, expden, resolution, out);
}

// Round 5
// 251.605 us; speedup vs baseline: 1.0093x; 1.0093x over previous
//
#include <hip/hip_runtime.h>
#include <math.h>

#define N_RES 768
#define DISTO_BINS 64
#define LDDT_BINS 50
#define DISTO_GRID 2048
#define EXP_GRID 64
#define NPAIRS (N_RES * N_RES)
#define NCHUNKS (NPAIRS / 4)

// 16-lane (DPP row) sum via row_ror rotations — pure VALU pipe, no LDS ops.
#define ROW_ADD_ROR(v, N)                                                     \
    v += __int_as_float(__builtin_amdgcn_update_dpp(                          \
        0, __float_as_int(v), 0x120 | (N), 0xF, 0xF, false))

// ---------------- Kernel P: per-pair bin + weight precompute ----------------
__global__ __launch_bounds__(256)
void pair_meta_kernel(const float* __restrict__ pb,
                      const float* __restrict__ pbm,
                      unsigned char* __restrict__ bins,   // (NPAIRS)
                      float* __restrict__ wgt) {          // (NPAIRS)
    int p = blockIdx.x * blockDim.x + threadIdx.x;
    if (p >= NPAIRS) return;
    int i = p / N_RES;
    int j = p - i * N_RES;
    float dx = pb[3 * i + 0] - pb[3 * j + 0];
    float dy = pb[3 * i + 1] - pb[3 * j + 1];
    float dz = pb[3 * i + 2] - pb[3 * j + 2];
    float d  = sqrtf(dx * dx + dy * dy + dz * dz);
    float t  = ceilf((d - 2.3125f) * 3.2f);     // 1/0.3125 = 3.2 exact
    int bin  = (int)fminf(fmaxf(t, 0.f), 63.f);
    bins[p]  = (unsigned char)bin;
    wgt[p]   = pbm[i] * pbm[j];
}

// ---------------- Kernel A: distogram CE partial sums ----------------
// Chunk = 4 pairs x 64 bins = 1024 B. Lane l holds float4 [4l,4l+4);
// lanes 16q..16q+15 hold pair q. Zero LDS-pipe ops in the hot loop:
// exp-sum via DPP row_ror, bin term via owner-lane predicated FMA.
__global__ __launch_bounds__(256)
void disto_partial_kernel(const float4* __restrict__ logits4,
                          const unsigned int* __restrict__ binw, // (NCHUNKS)
                          const float* __restrict__ wgt,         // (NPAIRS)
                          float* __restrict__ partial) {
    const int lane = threadIdx.x & 63;
    const int wid  = threadIdx.x >> 6;
    const int q    = lane >> 4;    // pair-group 0..3 within wave
    const int gl   = lane & 15;    // lane within group
    const int gw   = blockIdx.x * 4 + wid;
    const int nw   = DISTO_GRID * 4;                 // 8192 waves

    float acc = 0.f;

#define DISTO_PROC(xv4, cc)                                                   \
    {                                                                         \
        float e = __expf(xv4.x) + __expf(xv4.y) + __expf(xv4.z) +             \
                  __expf(xv4.w);                                              \
        ROW_ADD_ROR(e, 8);                                                    \
        ROW_ADD_ROR(e, 4);                                                    \
        ROW_ADD_ROR(e, 2);                                                    \
        ROW_ADD_ROR(e, 1);                                                    \
        unsigned int bw = binw[cc];                                           \
        int bin = (int)((bw >> (q * 8)) & 63u);                               \
        float w  = wgt[(cc) * 4 + q];                                         \
        float xs = (bin & 2) ? ((bin & 1) ? xv4.w : xv4.z)                    \
                             : ((bin & 1) ? xv4.y : xv4.x);                   \
        float lg = (gl == 0) ? w * __logf(e) : 0.f;                           \
        float bt = (gl == (bin >> 2)) ? w * xs : 0.f;                         \
        acc += lg - bt;                                                       \
    }

    for (int c0 = gw; c0 < NCHUNKS; c0 += 4 * nw) {
        const int c1 = c0 + nw;
        const int c2 = c0 + 2 * nw;
        const int c3 = c0 + 3 * nw;
        float4 x0 = logits4[(size_t)c0 * 64 + lane];
        float4 x1 = (c1 < NCHUNKS) ? logits4[(size_t)c1 * 64 + lane]
                                   : make_float4(0.f, 0.f, 0.f, 0.f);
        float4 x2 = (c2 < NCHUNKS) ? logits4[(size_t)c2 * 64 + lane]
                                   : make_float4(0.f, 0.f, 0.f, 0.f);
        float4 x3 = (c3 < NCHUNKS) ? logits4[(size_t)c3 * 64 + lane]
                                   : make_float4(0.f, 0.f, 0.f, 0.f);

        DISTO_PROC(x0, c0);
        if (c1 < NCHUNKS) DISTO_PROC(x1, c1);
        if (c2 < NCHUNKS) DISTO_PROC(x2, c2);
        if (c3 < NCHUNKS) DISTO_PROC(x3, c3);
    }
#undef DISTO_PROC

    // acc now lives on ALL 64 lanes (log-term on gl==0, bin-terms on owners)
    acc += __shfl_xor(acc, 1, 64);
    acc += __shfl_xor(acc, 2, 64);
    acc += __shfl_xor(acc, 4, 64);
    acc += __shfl_xor(acc, 8, 64);
    acc += __shfl_xor(acc, 16, 64);
    acc += __shfl_xor(acc, 32, 64);
    __shared__ float wsum[4];
    if (lane == 0) wsum[wid] = acc;
    __syncthreads();
    if (threadIdx.x == 0)
        partial[blockIdx.x] = wsum[0] + wsum[1] + wsum[2] + wsum[3];
}

// -------- Kernel B: fused per-residue lddt+CE  AND  exp-resolved partials --
__global__ __launch_bounds__(128)
void small_losses_kernel(const float* __restrict__ pred37,      // (N,37,3)
                         const float* __restrict__ true37,      // (N,37,3)
                         const float* __restrict__ mask37,      // (N,37)
                         const float* __restrict__ lddt_logits, // (N,50)
                         const float* __restrict__ exl,         // (N,37)
                         const float* __restrict__ a37ex,       // (N,37)
                         float* __restrict__ errm,              // (N)
                         float* __restrict__ expnum,            // (EXP_GRID)
                         float* __restrict__ expden) {          // (EXP_GRID)
    const int tid  = threadIdx.x;
    const int nthr = blockDim.x;
    __shared__ float r1[128], r2[128];

    if (blockIdx.x >= N_RES) {
        const int b = blockIdx.x - N_RES;
        const int gid = b * nthr + tid;
        const int stride = EXP_GRID * nthr;
        const int n = N_RES * 37;
        float num = 0.f, den = 0.f;
        for (int k = gid; k < n; k += stride) {
            float x  = exl[k];
            float m  = mask37[k];
            float ex = a37ex[k];
            float ax = fabsf(x);
            float sp = __logf(1.f + __expf(-ax));   // softplus(-|x|)
            float ls  = sp + fmaxf(-x, 0.f);        // -log_sigmoid(x)
            float lsn = sp + fmaxf(x, 0.f);         // -log_sigmoid(-x)
            float err = m * ls + (1.f - m) * lsn;
            num += err * ex;
            den += ex;
        }
        r1[tid] = num;
        r2[tid] = den;
        __syncthreads();
        for (int s = nthr >> 1; s > 0; s >>= 1) {
            if (tid < s) { r1[tid] += r1[tid + s]; r2[tid] += r2[tid + s]; }
            __syncthreads();
        }
        if (tid == 0) { expnum[b] = r1[0]; expden[b] = r2[0]; }
        return;
    }

    const int i = blockIdx.x;
    const float tix = true37[(i * 37 + 1) * 3 + 0];
    const float tiy = true37[(i * 37 + 1) * 3 + 1];
    const float tiz = true37[(i * 37 + 1) * 3 + 2];
    const float pix = pred37[(i * 37 + 1) * 3 + 0];
    const float piy = pred37[(i * 37 + 1) * 3 + 1];
    const float piz = pred37[(i * 37 + 1) * 3 + 2];
    const float mi  = mask37[i * 37 + 1];

    float scope_sum = 0.f, score_sum = 0.f;
    for (int j = tid; j < N_RES; j += nthr) {
        float mj  = mask37[j * 37 + 1];
        float dtx = tix - true37[(j * 37 + 1) * 3 + 0];
        float dty = tiy - true37[(j * 37 + 1) * 3 + 1];
        float dtz = tiz - true37[(j * 37 + 1) * 3 + 2];
        float dt  = sqrtf(1e-10f + dtx * dtx + dty * dty + dtz * dtz);
        float dpx = pix - pred37[(j * 37 + 1) * 3 + 0];
        float dpy = piy - pred37[(j * 37 + 1) * 3 + 1];
        float dpz = piz - pred37[(j * 37 + 1) * 3 + 2];
        float dp  = sqrtf(1e-10f + dpx * dpx + dpy * dpy + dpz * dpz);
        float scope = (dt < 15.f && j != i) ? (mi * mj) : 0.f;
        float l1 = fabsf(dt - dp);
        float sc = 0.25f * ((l1 < 0.5f ? 1.f : 0.f) + (l1 < 1.f ? 1.f : 0.f) +
                            (l1 < 2.f ? 1.f : 0.f) + (l1 < 4.f ? 1.f : 0.f));
        scope_sum += scope;
        score_sum += scope * sc;
    }

    r1[tid] = scope_sum;
    r2[tid] = score_sum;
    __syncthreads();
    for (int s = nthr >> 1; s > 0; s >>= 1) {
        if (tid < s) { r1[tid] += r1[tid + s]; r2[tid] += r2[tid + s]; }
        __syncthreads();
    }

    __shared__ int binS;
    if (tid == 0) {
        float lddt = (1e-10f + r2[0]) / (1e-10f + r1[0]);
        int bin = (int)floorf(lddt * (float)LDDT_BINS);
        binS = min(max(bin, 0), LDDT_BINS - 1);
    }
    __syncthreads();

    float e = (tid < LDDT_BINS) ? __expf(lddt_logits[i * LDDT_BINS + tid]) : 0.f;
    r1[tid] = e;
    __syncthreads();
    for (int s = nthr >> 1; s > 0; s >>= 1) {
        if (tid < s) r1[tid] += r1[tid + s];
        __syncthreads();
    }
    if (tid == 0) {
        float err = __logf(r1[0]) - lddt_logits[i * LDDT_BINS + binS];
        errm[i] = err * mi;
    }
}

// ---------------- Kernel C: final combine (small reductions only) --------
__global__ __launch_bounds__(256)
void finalize_kernel(const float* __restrict__ partial,  // (DISTO_GRID)
                     const float* __restrict__ pbm,      // (N,)
                     const float* __restrict__ errm,     // (N,)
                     const float* __restrict__ mask37,   // (N,37)
                     const float* __restrict__ expnum,   // (EXP_GRID)
                     const float* __restrict__ expden,   // (EXP_GRID)
                     const float* __restrict__ resolution,
                     float* __restrict__ out) {
    const int tid = threadIdx.x;
    const int nthr = blockDim.x;

    double sd = 0.0, sm = 0.0, se = 0.0, smca = 0.0, num = 0.0, den = 0.0;
    for (int k = tid; k < DISTO_GRID; k += nthr) sd += (double)partial[k];
    for (int k = tid; k < N_RES; k += nthr) {
        sm   += (double)pbm[k];
        se   += (double)errm[k];
        smca += (double)mask37[k * 37 + 1];
    }
    if (tid < EXP_GRID) { num = (double)expnum[tid]; den = (double)expden[tid]; }

    __shared__ double red[256];
    double vals[6] = {sd, sm, se, smca, num, den};
    double tot[6];
    for (int v = 0; v < 6; ++v) {
        red[tid] = vals[v];
        __syncthreads();
        for (int s = nthr >> 1; s > 0; s >>= 1) {
            if (tid < s) red[tid] += red[tid + s];
            __syncthreads();
        }
        tot[v] = red[0];
        __syncthreads();
    }

    if (tid == 0) {
        float res = resolution[0];
        double gate = (res >= 0.1f && res <= 3.0f) ? 1.0 : 0.0;
        double l_disto = tot[0] / (1e-6 + tot[1] * tot[1]);
        double l_plddt = tot[2] / (1e-10 + tot[3]) * gate;
        double l_exp   = tot[4] / (1e-8 + tot[5]) * gate;
        out[0] = (float)(0.3 * l_disto + 0.01 * l_plddt + 0.01 * l_exp);
    }
}

extern "C" void kernel_launch(void* const* d_in, const int* in_sizes, int n_in,
                              void* d_out, int out_size, void* d_ws, size_t ws_size,
                              hipStream_t stream) {
    const float* disto       = (const float*)d_in[0];  // (1,768,768,64)
    const float* pb          = (const float*)d_in[1];  // (1,768,3)
    const float* pbm         = (const float*)d_in[2];  // (1,768)
    const float* lddt_logits = (const float*)d_in[3];  // (1,768,50)
    const float* pred        = (const float*)d_in[4];  // (1,768,37,3)
    const float* truep       = (const float*)d_in[5];  // (1,768,37,3)
    const float* am          = (const float*)d_in[6];  // (1,768,37)
    const float* exl         = (const float*)d_in[7];  // (1,768,37)
    const float* a37         = (const float*)d_in[8];  // (1,768,37)
    const float* resolution  = (const float*)d_in[9];  // (1,)
    float* out = (float*)d_out;

    float* ws      = (float*)d_ws;
    float* partial = ws;                         // DISTO_GRID floats
    float* errm    = ws + DISTO_GRID;            // N_RES
    float* expnum  = errm + N_RES;               // EXP_GRID
    float* expden  = expnum + EXP_GRID;          // EXP_GRID
    float* wgt     = ws + 4096;                  // NPAIRS floats
    unsigned char* bins = (unsigned char*)(wgt + NPAIRS);  // NPAIRS bytes, 4B-aligned

    pair_meta_kernel<<<(NPAIRS + 255) / 256, 256, 0, stream>>>(pb, pbm, bins, wgt);
    disto_partial_kernel<<<DISTO_GRID, 256, 0, stream>>>(
        (const float4*)disto, (const unsigned int*)bins, wgt, partial);
    small_losses_kernel<<<N_RES + EXP_GRID, 128, 0, stream>>>(
        pred, truep, am, lddt_logits, exl, a37, errm, expnum, expden);
    finalize_kernel<<<1, 256, 0, stream>>>(partial, pbm, errm, am,
                                           expnum, expden, resolution, out);
}

// Round 7
// 237.228 us; speedup vs baseline: 1.0705x; 1.0606x over previous
//
#include <hip/hip_runtime.h>
#include <math.h>

#define N_RES 768
#define DISTO_BINS 64
#define LDDT_BINS 50
#define DISTO_BLOCKS 2048
#define LDDT_BLOCKS N_RES
#define EXP_GRID 64
#define NPAIRS (N_RES * N_RES)
#define NCHUNKS (NPAIRS / 4)          /* 147456 = 8192 waves * 18 */
#define CHUNKS_PER_WAVE 18

// native vector type accepted by __builtin_nontemporal_load
typedef float f32x4 __attribute__((ext_vector_type(4)));

// 16-lane (DPP row) sum via row_ror rotations — pure VALU pipe.
#define ROW_ADD_ROR(v, N)                                                     \
    v += __int_as_float(__builtin_amdgcn_update_dpp(                          \
        0, __float_as_int(v), 0x120 | (N), 0xF, 0xF, false))

// ---------------- Kernel P: per-pair bin + weight precompute ----------------
__global__ __launch_bounds__(256)
void pair_meta_kernel(const float* __restrict__ pb,
                      const float* __restrict__ pbm,
                      unsigned char* __restrict__ bins,   // (NPAIRS)
                      float* __restrict__ wgt) {          // (NPAIRS)
    int p = blockIdx.x * blockDim.x + threadIdx.x;
    if (p >= NPAIRS) return;
    int i = p / N_RES;
    int j = p - i * N_RES;
    float dx = pb[3 * i + 0] - pb[3 * j + 0];
    float dy = pb[3 * i + 1] - pb[3 * j + 1];
    float dz = pb[3 * i + 2] - pb[3 * j + 2];
    float d  = sqrtf(dx * dx + dy * dy + dz * dz);
    float t  = ceilf((d - 2.3125f) * 3.2f);     // 1/0.3125 = 3.2 exact
    int bin  = (int)fminf(fmaxf(t, 0.f), 63.f);
    bins[p]  = (unsigned char)bin;
    wgt[p]   = pbm[i] * pbm[j];
}

// ---------------- Kernel A (fused): disto stream + lddt + exp ---------------
// blocks [0, DISTO_BLOCKS)                 : distogram CE partial sums
// blocks [DISTO_BLOCKS, +N_RES)            : per-residue lddt + CE
// blocks [DISTO_BLOCKS+N_RES, +EXP_GRID)   : exp-resolved partial sums
__global__ __launch_bounds__(256)
void fused_main_kernel(const f32x4* __restrict__ logits4,
                       const unsigned int* __restrict__ binw, // (NCHUNKS)
                       const float* __restrict__ wgt,         // (NPAIRS)
                       const float* __restrict__ pred37,      // (N,37,3)
                       const float* __restrict__ true37,      // (N,37,3)
                       const float* __restrict__ mask37,      // (N,37)
                       const float* __restrict__ lddt_logits, // (N,50)
                       const float* __restrict__ exl,         // (N,37)
                       const float* __restrict__ a37ex,       // (N,37)
                       float* __restrict__ partial,           // (DISTO_BLOCKS)
                       float* __restrict__ errm,              // (N)
                       float* __restrict__ expnum,            // (EXP_GRID)
                       float* __restrict__ expden) {          // (EXP_GRID)
    __shared__ float r1[256], r2[256];
    const int tid  = threadIdx.x;
    const int nthr = blockDim.x;

    if (blockIdx.x < DISTO_BLOCKS) {
        // ================= distogram partial sums =================
        const int lane = tid & 63;
        const int wid  = tid >> 6;
        const int q    = lane >> 4;    // pair-group 0..3 within wave
        const int gl   = lane & 15;    // lane within group
        const int gw   = blockIdx.x * 4 + wid;          // wave id 0..8191
        const int base = gw * CHUNKS_PER_WAVE;          // contiguous 18 KB

        float acc = 0.f;

#define DISTO_PROC(xv4, cc)                                                   \
    {                                                                         \
        float e = __expf(xv4.x) + __expf(xv4.y) + __expf(xv4.z) +             \
                  __expf(xv4.w);                                              \
        ROW_ADD_ROR(e, 8);                                                    \
        ROW_ADD_ROR(e, 4);                                                    \
        ROW_ADD_ROR(e, 2);                                                    \
        ROW_ADD_ROR(e, 1);                                                    \
        unsigned int bw = binw[cc];                                           \
        int bin = (int)((bw >> (q * 8)) & 63u);                               \
        float w  = wgt[(cc) * 4 + q];                                         \
        float xs = (bin & 2) ? ((bin & 1) ? xv4.w : xv4.z)                    \
                             : ((bin & 1) ? xv4.y : xv4.x);                   \
        float lg = (gl == 0) ? w * __logf(e) : 0.f;                           \
        float bt = (gl == (bin >> 2)) ? w * xs : 0.f;                         \
        acc += lg - bt;                                                       \
    }

#pragma unroll
        for (int t3 = 0; t3 < 3; ++t3) {
            const int cb = base + t3 * 6;
            f32x4 x0 = __builtin_nontemporal_load(
                &logits4[(size_t)(cb + 0) * 64 + lane]);
            f32x4 x1 = __builtin_nontemporal_load(
                &logits4[(size_t)(cb + 1) * 64 + lane]);
            f32x4 x2 = __builtin_nontemporal_load(
                &logits4[(size_t)(cb + 2) * 64 + lane]);
            f32x4 x3 = __builtin_nontemporal_load(
                &logits4[(size_t)(cb + 3) * 64 + lane]);
            f32x4 x4 = __builtin_nontemporal_load(
                &logits4[(size_t)(cb + 4) * 64 + lane]);
            f32x4 x5 = __builtin_nontemporal_load(
                &logits4[(size_t)(cb + 5) * 64 + lane]);
            DISTO_PROC(x0, cb + 0);
            DISTO_PROC(x1, cb + 1);
            DISTO_PROC(x2, cb + 2);
            DISTO_PROC(x3, cb + 3);
            DISTO_PROC(x4, cb + 4);
            DISTO_PROC(x5, cb + 5);
        }
#undef DISTO_PROC

        // acc lives on all 64 lanes (log-term on gl==0, bin-terms on owners)
        acc += __shfl_xor(acc, 1, 64);
        acc += __shfl_xor(acc, 2, 64);
        acc += __shfl_xor(acc, 4, 64);
        acc += __shfl_xor(acc, 8, 64);
        acc += __shfl_xor(acc, 16, 64);
        acc += __shfl_xor(acc, 32, 64);
        if (lane == 0) r1[wid] = acc;
        __syncthreads();
        if (tid == 0)
            partial[blockIdx.x] = r1[0] + r1[1] + r1[2] + r1[3];
        return;
    }

    if (blockIdx.x >= DISTO_BLOCKS + LDDT_BLOCKS) {
        // ================= exp-resolved partial sums =================
        const int b = blockIdx.x - DISTO_BLOCKS - LDDT_BLOCKS;
        const int gid = b * nthr + tid;
        const int stride = EXP_GRID * nthr;
        const int n = N_RES * 37;
        float num = 0.f, den = 0.f;
        for (int k = gid; k < n; k += stride) {
            float x  = exl[k];
            float m  = mask37[k];
            float ex = a37ex[k];
            float ax = fabsf(x);
            float sp = __logf(1.f + __expf(-ax));   // softplus(-|x|)
            float ls  = sp + fmaxf(-x, 0.f);        // -log_sigmoid(x)
            float lsn = sp + fmaxf(x, 0.f);         // -log_sigmoid(-x)
            float err = m * ls + (1.f - m) * lsn;
            num += err * ex;
            den += ex;
        }
        r1[tid] = num;
        r2[tid] = den;
        __syncthreads();
        for (int s = nthr >> 1; s > 0; s >>= 1) {
            if (tid < s) { r1[tid] += r1[tid + s]; r2[tid] += r2[tid + s]; }
            __syncthreads();
        }
        if (tid == 0) { expnum[b] = r1[0]; expden[b] = r2[0]; }
        return;
    }

    // ================= per-residue lddt + CE =================
    const int i = blockIdx.x - DISTO_BLOCKS;
    const float tix = true37[(i * 37 + 1) * 3 + 0];
    const float tiy = true37[(i * 37 + 1) * 3 + 1];
    const float tiz = true37[(i * 37 + 1) * 3 + 2];
    const float pix = pred37[(i * 37 + 1) * 3 + 0];
    const float piy = pred37[(i * 37 + 1) * 3 + 1];
    const float piz = pred37[(i * 37 + 1) * 3 + 2];
    const float mi  = mask37[i * 37 + 1];

    float scope_sum = 0.f, score_sum = 0.f;
    for (int j = tid; j < N_RES; j += nthr) {
        float mj  = mask37[j * 37 + 1];
        float dtx = tix - true37[(j * 37 + 1) * 3 + 0];
        float dty = tiy - true37[(j * 37 + 1) * 3 + 1];
        float dtz = tiz - true37[(j * 37 + 1) * 3 + 2];
        float dt  = sqrtf(1e-10f + dtx * dtx + dty * dty + dtz * dtz);
        float dpx = pix - pred37[(j * 37 + 1) * 3 + 0];
        float dpy = piy - pred37[(j * 37 + 1) * 3 + 1];
        float dpz = piz - pred37[(j * 37 + 1) * 3 + 2];
        float dp  = sqrtf(1e-10f + dpx * dpx + dpy * dpy + dpz * dpz);
        float scope = (dt < 15.f && j != i) ? (mi * mj) : 0.f;
        float l1 = fabsf(dt - dp);
        float sc = 0.25f * ((l1 < 0.5f ? 1.f : 0.f) + (l1 < 1.f ? 1.f : 0.f) +
                            (l1 < 2.f ? 1.f : 0.f) + (l1 < 4.f ? 1.f : 0.f));
        scope_sum += scope;
        score_sum += scope * sc;
    }

    r1[tid] = scope_sum;
    r2[tid] = score_sum;
    __syncthreads();
    for (int s = nthr >> 1; s > 0; s >>= 1) {
        if (tid < s) { r1[tid] += r1[tid + s]; r2[tid] += r2[tid + s]; }
        __syncthreads();
    }

    __shared__ int binS;
    if (tid == 0) {
        float lddt = (1e-10f + r2[0]) / (1e-10f + r1[0]);
        int bin = (int)floorf(lddt * (float)LDDT_BINS);
        binS = min(max(bin, 0), LDDT_BINS - 1);
    }
    __syncthreads();

    float e = (tid < LDDT_BINS) ? __expf(lddt_logits[i * LDDT_BINS + tid]) : 0.f;
    r1[tid] = e;
    __syncthreads();
    for (int s = nthr >> 1; s > 0; s >>= 1) {
        if (tid < s) r1[tid] += r1[tid + s];
        __syncthreads();
    }
    if (tid == 0) {
        float err = __logf(r1[0]) - lddt_logits[i * LDDT_BINS + binS];
        errm[i] = err * mi;
    }
}

// ---------------- Kernel C: final combine (small reductions only) --------
__global__ __launch_bounds__(256)
void finalize_kernel(const float* __restrict__ partial,  // (DISTO_BLOCKS)
                     const float* __restrict__ pbm,      // (N,)
                     const float* __restrict__ errm,     // (N,)
                     const float* __restrict__ mask37,   // (N,37)
                     const float* __restrict__ expnum,   // (EXP_GRID)
                     const float* __restrict__ expden,   // (EXP_GRID)
                     const float* __restrict__ resolution,
                     float* __restrict__ out) {
    const int tid = threadIdx.x;
    const int nthr = blockDim.x;

    double sd = 0.0, sm = 0.0, se = 0.0, smca = 0.0, num = 0.0, den = 0.0;
    for (int k = tid; k < DISTO_BLOCKS; k += nthr) sd += (double)partial[k];
    for (int k = tid; k < N_RES; k += nthr) {
        sm   += (double)pbm[k];
        se   += (double)errm[k];
        smca += (double)mask37[k * 37 + 1];
    }
    if (tid < EXP_GRID) { num = (double)expnum[tid]; den = (double)expden[tid]; }

    __shared__ double red[256];
    double vals[6] = {sd, sm, se, smca, num, den};
    double tot[6];
    for (int v = 0; v < 6; ++v) {
        red[tid] = vals[v];
        __syncthreads();
        for (int s = nthr >> 1; s > 0; s >>= 1) {
            if (tid < s) red[tid] += red[tid + s];
            __syncthreads();
        }
        tot[v] = red[0];
        __syncthreads();
    }

    if (tid == 0) {
        float res = resolution[0];
        double gate = (res >= 0.1f && res <= 3.0f) ? 1.0 : 0.0;
        double l_disto = tot[0] / (1e-6 + tot[1] * tot[1]);
        double l_plddt = tot[2] / (1e-10 + tot[3]) * gate;
        double l_exp   = tot[4] / (1e-8 + tot[5]) * gate;
        out[0] = (float)(0.3 * l_disto + 0.01 * l_plddt + 0.01 * l_exp);
    }
}

extern "C" void kernel_launch(void* const* d_in, const int* in_sizes, int n_in,
                              void* d_out, int out_size, void* d_ws, size_t ws_size,
                              hipStream_t stream) {
    const float* disto       = (const float*)d_in[0];  // (1,768,768,64)
    const float* pb          = (const float*)d_in[1];  // (1,768,3)
    const float* pbm         = (const float*)d_in[2];  // (1,768)
    const float* lddt_logits = (const float*)d_in[3];  // (1,768,50)
    const float* pred        = (const float*)d_in[4];  // (1,768,37,3)
    const float* truep       = (const float*)d_in[5];  // (1,768,37,3)
    const float* am          = (const float*)d_in[6];  // (1,768,37)
    const float* exl         = (const float*)d_in[7];  // (1,768,37)
    const float* a37         = (const float*)d_in[8];  // (1,768,37)
    const float* resolution  = (const float*)d_in[9];  // (1,)
    float* out = (float*)d_out;

    float* ws      = (float*)d_ws;
    float* partial = ws;                         // DISTO_BLOCKS floats
    float* errm    = ws + DISTO_BLOCKS;          // N_RES
    float* expnum  = errm + N_RES;               // EXP_GRID
    float* expden  = expnum + EXP_GRID;          // EXP_GRID
    float* wgt     = ws + 4096;                  // NPAIRS floats
    unsigned char* bins = (unsigned char*)(wgt + NPAIRS);  // NPAIRS bytes

    pair_meta_kernel<<<(NPAIRS + 255) / 256, 256, 0, stream>>>(pb, pbm, bins, wgt);
    fused_main_kernel<<<DISTO_BLOCKS + LDDT_BLOCKS + EXP_GRID, 256, 0, stream>>>(
        (const f32x4*)disto, (const unsigned int*)bins, wgt,
        pred, truep, am, lddt_logits, exl, a37,
        partial, errm, expnum, expden);
    finalize_kernel<<<1, 256, 0, stream>>>(partial, pbm, errm, am,
                                           expnum, expden, resolution, out);
}